// Round 2
// baseline (339.041 us; speedup 1.0000x reference)
//
#include <hip/hip_runtime.h>
#include <hip/hip_bf16.h>
#include <stdint.h>

typedef short s8v __attribute__((ext_vector_type(8)));
typedef float f4v __attribute__((ext_vector_type(4)));

__device__ __align__(16) float g_zeros[4] = {0.f, 0.f, 0.f, 0.f};

__device__ __forceinline__ void async_copy16(const void* gsrc, void* lds_dst) {
  __builtin_amdgcn_global_load_lds(
      (const __attribute__((address_space(1))) uint32_t*)(uintptr_t)gsrc,
      (__attribute__((address_space(3))) uint32_t*)(uint32_t)(uintptr_t)lds_dst,
      16, 0, 0);
}

// ---------------- W pack: [co][ci][kh][kw] fp32 -> [kh*5+kw][co][ci] bf16 ----------------
__global__ void wpack_kernel(const float* __restrict__ W, __hip_bfloat16* __restrict__ Wr) {
  int i = blockIdx.x * 256 + threadIdx.x;  // < 819200
  int ci = i & 255;
  int rest = i >> 8;
  int co = rest & 127;
  int pos = rest >> 7;  // kh*5+kw
  Wr[i] = __float2bfloat16(W[(co * 256 + ci) * 25 + pos]);
}

// ---------------- Upsample: x NCHW fp32 (8,256,64,64) -> up NHWC bf16 (8,128,128,256) ----------------
// grid: b(8) x cb(4,64ch) x ohb(8,16 rows) x owb(2,64 cols) = 512 blocks
__global__ __launch_bounds__(256, 2) void upsample_kernel(const float* __restrict__ x,
                                                          __hip_bfloat16* __restrict__ up) {
  __shared__ __hip_bfloat16 lx[10 * 48 * 66];  // [ih 10][iw 48][c 64 + 2 pad]
  const int tid = threadIdx.x;
  const int bx = blockIdx.x;
  const int owb = bx & 1;
  const int ohb = (bx >> 1) & 7;
  const int cb = (bx >> 4) & 3;
  const int b = bx >> 6;
  const int oh0 = ohb * 16, ow0 = owb * 64, c0 = cb * 64;
  const int ih0 = (oh0 >> 1) - 1;                    // may be -1
  const int iw_lo = (ow0 >> 1) - 1;
  const int aligned = (iw_lo < 0 ? 0 : iw_lo) & ~15; // 0 or 16

  for (int i = tid; i < 64 * 10 * 12; i += 256) {    // float4 loads along iw
    int c = i / 120;
    int rem = i - c * 120;
    int r = rem / 12;
    int w4 = (rem - r * 12) * 4;
    int gr = ih0 + r;
    gr = gr < 0 ? 0 : (gr > 63 ? 63 : gr);
    const float4 v = *(const float4*)&x[(((b * 256 + c0 + c) * 64) + gr) * 64 + aligned + w4];
    int base = (r * 48 + w4) * 66 + c;
    lx[base]       = __float2bfloat16(v.x);
    lx[base + 66]  = __float2bfloat16(v.y);
    lx[base + 132] = __float2bfloat16(v.z);
    lx[base + 198] = __float2bfloat16(v.w);
  }
  __syncthreads();

  // 2 channels per thread: b32 LDS reads, packed bf16x2 global stores
  const int c2 = (tid & 31) * 2;
  const int owq = tid >> 5;  // 0..7
  uint32_t* upu = (uint32_t*)up;
  for (int it = 0; it < 128; ++it) {
    int oh_l = it >> 3;
    int ow_l = (it & 7) * 8 + owq;
    int oh = oh0 + oh_l, ow = ow0 + ow_l;
    int ihA = (oh >> 1) - ((oh & 1) ^ 1);            // first tap row
    float wh = (oh & 1) ? 0.75f : 0.25f;             // its weight
    int iwA = (ow >> 1) - ((ow & 1) ^ 1);
    float wwt = (ow & 1) ? 0.75f : 0.25f;
    int r0 = ihA - ih0;                               // slot content is pre-clamped
    int w0 = (iwA < 0 ? 0 : iwA) - aligned;
    int w1t = iwA + 1; w1t = w1t > 63 ? 63 : w1t;
    int w1 = w1t - aligned;
    uint32_t t00 = *(const uint32_t*)&lx[(r0 * 48 + w0) * 66 + c2];
    uint32_t t01 = *(const uint32_t*)&lx[(r0 * 48 + w1) * 66 + c2];
    uint32_t t10 = *(const uint32_t*)&lx[((r0 + 1) * 48 + w0) * 66 + c2];
    uint32_t t11 = *(const uint32_t*)&lx[((r0 + 1) * 48 + w1) * 66 + c2];
    float wlo = wh * wwt, wlo1 = wh * (1.f - wwt);
    float whi = (1.f - wh) * wwt, whi1 = (1.f - wh) * (1.f - wwt);
    float vlo = wlo * __uint_as_float(t00 << 16) + wlo1 * __uint_as_float(t01 << 16) +
                whi * __uint_as_float(t10 << 16) + whi1 * __uint_as_float(t11 << 16);
    float vhi = wlo * __uint_as_float(t00 & 0xffff0000u) + wlo1 * __uint_as_float(t01 & 0xffff0000u) +
                whi * __uint_as_float(t10 & 0xffff0000u) + whi1 * __uint_as_float(t11 & 0xffff0000u);
    __hip_bfloat16 h0 = __float2bfloat16(vlo);
    __hip_bfloat16 h1 = __float2bfloat16(vhi);
    uint32_t pk = (uint32_t)(*(unsigned short*)&h0) | ((uint32_t)(*(unsigned short*)&h1) << 16);
    upu[((((size_t)(b * 128 + oh) * 128) + ow) * 256 + c0 + c2) >> 1] = pk;
  }
}

// ---------------- Conv: implicit GEMM, M=256 (4 rows x 64 ow) x N=128 couts, MFMA bf16 ----------------
// grid: 512 blocks (2 per CU) = b(8) x ohg(32) x owh(2), 512 threads (8 waves: 4 rows x 2 cout-halves)
// lA: 5-slot circular row window [72 iw+halo][64 ch] XOR-swizzled; prefetch at kw==2 (5-slot safe).
// lB: double-buffered [128 cout][64 ch]; next (kh,kw) prefetched before compute -> 1 barrier/round.
// 78 KB LDS -> 2 blocks/CU -> 4 waves/SIMD latency hiding.
#define ASLOT 4608  // shorts per lA slot (72 rows * 64 ch)
__global__ __launch_bounds__(512, 4) void conv_kernel(const __hip_bfloat16* __restrict__ up,
                                                      const __hip_bfloat16* __restrict__ Wr,
                                                      float* __restrict__ out,
                                                      float* __restrict__ gstats) {
  __shared__ __align__(16) unsigned short lA[5 * ASLOT];     // 46080 B
  __shared__ __align__(16) unsigned short lB[2][128 * 64];   // 32768 B
  __shared__ float lsum[128], lssq[128];

  const int tid = threadIdx.x;
  const int lane = tid & 63;
  const int wave = tid >> 6;
  const int wm = wave >> 1;   // output row within 4-row group
  const int wn = wave & 1;    // cout half
  const int lane15 = lane & 15;
  const int quad = lane >> 4;

  const int bid = blockIdx.x;
  const int orig = ((bid & 7) << 6) | (bid >> 3);  // XCD-chunked: each XCD owns one batch image
  const int b = orig >> 6;
  const int oh0 = ((orig >> 1) & 31) << 2;
  const int owh = orig & 1;
  const int ow0 = owh << 6;

  const f4v zero4 = {0.f, 0.f, 0.f, 0.f};
  if (tid < 128) { lsum[tid] = 0.f; lssq[tid] = 0.f; }
  // zero the always-out-of-range iw chunks once (iw range is fixed per block; slots cycle ih only)
  if (owh == 0) {  // rows 0..3 <-> iw -4..-1
    for (int i = tid; i < 5 * 32; i += 512) {
      int s = i >> 5, rem = i & 31;
      *(f4v*)&lA[(s * 576 + (rem >> 3) * 8 + (rem & 7)) * 8] = zero4;
    }
  } else {         // rows 66..71 <-> iw 128..133
    for (int i = tid; i < 5 * 48; i += 512) {
      int s = i / 48, rem = i - s * 48;
      *(f4v*)&lA[(s * 576 + (66 + (rem >> 3)) * 8 + (rem & 7)) * 8] = zero4;
    }
  }

  auto stageA = [&](int slot, const __hip_bfloat16* uprow) {
    int idx = (wave << 6) + lane;
    int r = idx >> 3, pc = idx & 7;
    int cq = pc ^ (r & 7);
    int iw = ow0 - 4 + r;
    const void* src = ((unsigned)iw < 128u) ? (const void*)(uprow + iw * 256 + cq * 8)
                                            : (const void*)g_zeros;
    async_copy16(src, (void*)&lA[(slot * 576 + (wave << 6)) * 8]);
    if (wave == 0) {  // tail chunks 512..575 (wave-uniform branch, full wave)
      int idx2 = 512 + lane;
      int r2 = idx2 >> 3, pc2 = idx2 & 7;
      int cq2 = pc2 ^ (r2 & 7);
      int iw2 = ow0 - 4 + r2;
      const void* src2 = ((unsigned)iw2 < 128u) ? (const void*)(uprow + iw2 * 256 + cq2 * 8)
                                                : (const void*)g_zeros;
      async_copy16(src2, (void*)&lA[(slot * 576 + 512) * 8]);
    }
  };
  auto stageB = [&](const __hip_bfloat16* wrow, int bsel) {
#pragma unroll
    for (int t = 0; t < 2; ++t) {
      int base = t * 512 + (wave << 6);
      int idx = base + lane;
      int n = idx >> 3, pc = idx & 7;
      int cq = pc ^ (n & 7);
      async_copy16(wrow + n * 256 + cq * 8, (void*)&lB[bsel][base * 8]);
    }
  };

  f4v acc[4][4];
#pragma unroll
  for (int i = 0; i < 4; ++i)
#pragma unroll
    for (int j = 0; j < 4; ++j) acc[i][j] = zero4;

  // ---- prologue: prime lA rows oh0-2..oh0+1 (cb=0) + lB pos0 (cb=0)
  for (int rr = 0; rr < 4; ++rr) {
    int ih = oh0 + rr - 2;
    if ((unsigned)ih < 128u)
      stageA(ih % 5, up + (size_t)(b * 128 + ih) * 128 * 256);
  }
  stageB(Wr, 0);
  __syncthreads();

  int buf = 0;
  for (int cb = 0; cb < 4; ++cb) {
    const int c0 = cb << 6;
    for (int kh = 0; kh < 5; ++kh) {
      const int ih = oh0 + wm + kh - 2;
      const bool rowok = (unsigned)ih < 128u;
      const int abase = rowok ? (ih % 5) * ASLOT : 0;
      for (int kw = 0; kw < 5; ++kw) {
        const int pos = kh * 5 + kw;
        if (pos < 24) {  // prefetch next round's lB
          stageB(Wr + (size_t)(pos + 1) * 32768 + c0, buf ^ 1);
        } else if (cb < 3) {  // last pos: prefetch next cb's pos0
          stageB(Wr + (c0 + 64), buf ^ 1);
        }
        if (kw == 2 && kh < 4) {  // prefetch lA row for kh+1 (slot safe: retired row's
          int ihp = oh0 + kh + 2;  // last read was kh-1,kw4 -- two rounds ago)
          if (ihp < 128)
            stageA(ihp % 5, up + (size_t)(b * 128 + ihp) * 128 * 256 + c0);
        }
        if (rowok) {  // wave-uniform; barriers stay outside
#pragma unroll
          for (int ks = 0; ks < 2; ++ks) {
            const int cq = ks * 4 + quad;
            s8v a[4], bb[4];
#pragma unroll
            for (int mt = 0; mt < 4; ++mt) {
              int r = mt * 16 + lane15 + kw + 2;  // +2: lA row r <-> iw = ow0-4+r
              a[mt] = *(const s8v*)&lA[abase + (r * 8 + (cq ^ (r & 7))) * 8];
            }
#pragma unroll
            for (int nt = 0; nt < 4; ++nt) {
              int n = (wn << 6) + nt * 16 + lane15;
              bb[nt] = *(const s8v*)&lB[buf][(n * 8 + (cq ^ (n & 7))) * 8];
            }
#pragma unroll
            for (int mt = 0; mt < 4; ++mt)
#pragma unroll
              for (int nt = 0; nt < 4; ++nt)
                acc[mt][nt] = __builtin_amdgcn_mfma_f32_16x16x32_bf16(a[mt], bb[nt], acc[mt][nt], 0, 0, 0);
          }
        }
        __syncthreads();  // drains this round's prefetches; next round reads them
        buf ^= 1;
      }
    }
    if (cb < 3) {  // cb boundary: re-prime lA window for next cb's channels
      const int c0n = (cb + 1) << 6;
      for (int rr = 0; rr < 4; ++rr) {
        int ihn = oh0 + rr - 2;
        if ((unsigned)ihn < 128u)
          stageA(ihn % 5, up + (size_t)(b * 128 + ihn) * 128 * 256 + c0n);
      }
      __syncthreads();
    }
  }

  // ---- epilogue: direct stores from acc (D: cout=lane&15, ow=mt*16+quad*4+reg) + stats
  const int oh = oh0 + wm;
#pragma unroll
  for (int nt = 0; nt < 4; ++nt) {
    const int n = (wn << 6) + nt * 16 + lane15;
    float* oc = out + ((size_t)(b * 128 + n) * 128 + oh) * 128 + ow0;
    float s = 0.f, ss = 0.f;
#pragma unroll
    for (int mt = 0; mt < 4; ++mt) {
      f4v v = acc[mt][nt];
      *(f4v*)&oc[mt * 16 + (quad << 2)] = v;
      s += v.x + v.y + v.z + v.w;
      ss += v.x * v.x + v.y * v.y + v.z * v.z + v.w * v.w;
    }
    s += __shfl_xor(s, 16, 64); ss += __shfl_xor(ss, 16, 64);
    s += __shfl_xor(s, 32, 64); ss += __shfl_xor(ss, 32, 64);
    if (quad == 0) { atomicAdd(&lsum[n], s); atomicAdd(&lssq[n], ss); }
  }
  __syncthreads();
  if (tid < 128) {
    atomicAdd(&gstats[tid], lsum[tid]);
    atomicAdd(&gstats[128 + tid], lssq[tid]);
  }
}

// ---------------- BN scale/bias from accumulated stats ----------------
__global__ void scalebias_kernel(const float* __restrict__ gstats, const float* __restrict__ gamma,
                                 const float* __restrict__ beta, float* __restrict__ sb) {
  int c = threadIdx.x;
  float mean = gstats[c] * (1.f / 131072.f);
  float var = gstats[128 + c] * (1.f / 131072.f) - mean * mean;
  float inv = gamma[c] * rsqrtf(var + 1e-5f);
  sb[c] = inv;
  sb[128 + c] = beta[c] - mean * inv;
}

// ---------------- Normalize + ReLU in-place on d_out ----------------
__global__ void norm_kernel(float* __restrict__ out, const float* __restrict__ sb) {
  int i = blockIdx.x * 256 + threadIdx.x;  // float4 index, 4194304 total
  f4v v = ((f4v*)out)[i];
  int c = (i >> 12) & 127;
  float sc = sb[c], bi = sb[128 + c];
  v.x = fmaxf(fmaf(v.x, sc, bi), 0.f);
  v.y = fmaxf(fmaf(v.y, sc, bi), 0.f);
  v.z = fmaxf(fmaf(v.z, sc, bi), 0.f);
  v.w = fmaxf(fmaf(v.w, sc, bi), 0.f);
  ((f4v*)out)[i] = v;
}

extern "C" void kernel_launch(void* const* d_in, const int* in_sizes, int n_in,
                              void* d_out, int out_size, void* d_ws, size_t ws_size,
                              hipStream_t stream) {
  (void)in_sizes; (void)n_in; (void)out_size; (void)ws_size;
  const float* x = (const float*)d_in[0];
  const float* W = (const float*)d_in[1];
  const float* gamma = (const float*)d_in[2];
  const float* beta = (const float*)d_in[3];
  float* out = (float*)d_out;
  char* ws = (char*)d_ws;
  __hip_bfloat16* up = (__hip_bfloat16*)ws;                       // 67,108,864 B
  __hip_bfloat16* Wr = (__hip_bfloat16*)(ws + 67108864);          // 1,638,400 B
  float* gstats = (float*)(ws + 67108864 + 1638400);              // sum[128], sumsq[128]
  float* sb = gstats + 256;                                       // scale[128], bias[128]

  hipMemsetAsync(gstats, 0, 256 * sizeof(float), stream);
  wpack_kernel<<<3200, 256, 0, stream>>>(W, Wr);
  upsample_kernel<<<512, 256, 0, stream>>>(x, up);
  conv_kernel<<<512, 512, 0, stream>>>(up, Wr, out, gstats);
  scalebias_kernel<<<1, 128, 0, stream>>>(gstats, gamma, beta, sb);
  norm_kernel<<<16384, 256, 0, stream>>>(out, sb);
}

// Round 3
// 306.933 us; speedup vs baseline: 1.1046x; 1.1046x over previous
//
#include <hip/hip_runtime.h>
#include <hip/hip_bf16.h>
#include <stdint.h>

typedef short s8v __attribute__((ext_vector_type(8)));
typedef float f4v __attribute__((ext_vector_type(4)));

__device__ __forceinline__ void async_copy16(const void* gsrc, void* lds_dst) {
  __builtin_amdgcn_global_load_lds(
      (const __attribute__((address_space(1))) uint32_t*)(uintptr_t)gsrc,
      (__attribute__((address_space(3))) uint32_t*)(uint32_t)(uintptr_t)lds_dst,
      16, 0, 0);
}

#define WAITVM(N) asm volatile("s_waitcnt vmcnt(" #N ")" ::: "memory")
__device__ __forceinline__ void block_barrier() {
  asm volatile("" ::: "memory");
  __builtin_amdgcn_s_barrier();
  asm volatile("" ::: "memory");
}

// ---------------- W pack: [co][ci][kh][kw] fp32 -> [kh*5+kw][co][ci] bf16 ----------------
// One block per co; coalesced reads (contiguous 6400 floats) and coalesced writes (256-wide).
// Block 0 also zeroes gstats (replaces the hipMemsetAsync node).
__global__ __launch_bounds__(256) void wpack_kernel(const float* __restrict__ W,
                                                    __hip_bfloat16* __restrict__ Wr,
                                                    float* __restrict__ gstats) {
  __shared__ __hip_bfloat16 t[256 * 26];  // [ci][pos], pad to 26
  const int co = blockIdx.x;
  const int tid = threadIdx.x;
  if (co == 0) gstats[tid] = 0.f;  // 256 floats: sum[128], ssq[128]
  const float* src = W + co * 6400;
  for (int i = tid; i < 6400; i += 256) {
    int ci = i / 25;
    int pos = i - ci * 25;
    t[ci * 26 + pos] = __float2bfloat16(src[i]);
  }
  __syncthreads();
  for (int pos = 0; pos < 25; ++pos)
    Wr[pos * 32768 + co * 256 + tid] = t[tid * 26 + pos];
}

// ---------------- Upsample: x NCHW fp32 (8,256,64,64) -> up NHWC bf16 (8,128,128,256) ----------------
// grid: b(8) x cb(4,64ch) x ohb(8,16 rows) x owb(2,64 cols) = 512 blocks
__global__ __launch_bounds__(256, 2) void upsample_kernel(const float* __restrict__ x,
                                                          __hip_bfloat16* __restrict__ up) {
  __shared__ __hip_bfloat16 lx[10 * 48 * 66];  // [ih 10][iw 48][c 64 + 2 pad]
  const int tid = threadIdx.x;
  const int bx = blockIdx.x;
  const int owb = bx & 1;
  const int ohb = (bx >> 1) & 7;
  const int cb = (bx >> 4) & 3;
  const int b = bx >> 6;
  const int oh0 = ohb * 16, ow0 = owb * 64, c0 = cb * 64;
  const int ih0 = (oh0 >> 1) - 1;                    // may be -1
  const int iw_lo = (ow0 >> 1) - 1;
  const int aligned = (iw_lo < 0 ? 0 : iw_lo) & ~15; // 0 or 16

  for (int i = tid; i < 64 * 10 * 12; i += 256) {    // float4 loads along iw
    int c = i / 120;
    int rem = i - c * 120;
    int r = rem / 12;
    int w4 = (rem - r * 12) * 4;
    int gr = ih0 + r;
    gr = gr < 0 ? 0 : (gr > 63 ? 63 : gr);
    const float4 v = *(const float4*)&x[(((b * 256 + c0 + c) * 64) + gr) * 64 + aligned + w4];
    int base = (r * 48 + w4) * 66 + c;
    lx[base]       = __float2bfloat16(v.x);
    lx[base + 66]  = __float2bfloat16(v.y);
    lx[base + 132] = __float2bfloat16(v.z);
    lx[base + 198] = __float2bfloat16(v.w);
  }
  __syncthreads();

  // 2 channels per thread: b32 LDS reads, packed bf16x2 global stores
  const int c2 = (tid & 31) * 2;
  const int owq = tid >> 5;  // 0..7
  uint32_t* upu = (uint32_t*)up;
  for (int it = 0; it < 128; ++it) {
    int oh_l = it >> 3;
    int ow_l = (it & 7) * 8 + owq;
    int oh = oh0 + oh_l, ow = ow0 + ow_l;
    int ihA = (oh >> 1) - ((oh & 1) ^ 1);            // first tap row
    float wh = (oh & 1) ? 0.75f : 0.25f;             // its weight
    int iwA = (ow >> 1) - ((ow & 1) ^ 1);
    float wwt = (ow & 1) ? 0.75f : 0.25f;
    int r0 = ihA - ih0;                               // slot content is pre-clamped
    int w0 = (iwA < 0 ? 0 : iwA) - aligned;
    int w1t = iwA + 1; w1t = w1t > 63 ? 63 : w1t;
    int w1 = w1t - aligned;
    uint32_t t00 = *(const uint32_t*)&lx[(r0 * 48 + w0) * 66 + c2];
    uint32_t t01 = *(const uint32_t*)&lx[(r0 * 48 + w1) * 66 + c2];
    uint32_t t10 = *(const uint32_t*)&lx[((r0 + 1) * 48 + w0) * 66 + c2];
    uint32_t t11 = *(const uint32_t*)&lx[((r0 + 1) * 48 + w1) * 66 + c2];
    float wlo = wh * wwt, wlo1 = wh * (1.f - wwt);
    float whi = (1.f - wh) * wwt, whi1 = (1.f - wh) * (1.f - wwt);
    float vlo = wlo * __uint_as_float(t00 << 16) + wlo1 * __uint_as_float(t01 << 16) +
                whi * __uint_as_float(t10 << 16) + whi1 * __uint_as_float(t11 << 16);
    float vhi = wlo * __uint_as_float(t00 & 0xffff0000u) + wlo1 * __uint_as_float(t01 & 0xffff0000u) +
                whi * __uint_as_float(t10 & 0xffff0000u) + whi1 * __uint_as_float(t11 & 0xffff0000u);
    __hip_bfloat16 h0 = __float2bfloat16(vlo);
    __hip_bfloat16 h1 = __float2bfloat16(vhi);
    uint32_t pk = (uint32_t)(*(unsigned short*)&h0) | ((uint32_t)(*(unsigned short*)&h1) << 16);
    upu[((((size_t)(b * 128 + oh) * 128) + ow) * 256 + c0 + c2) >> 1] = pk;
  }
}

// ---------------- Conv: implicit GEMM, M=512 (4 rows x 128 ow) x N=128 couts, MFMA bf16 ----------------
// grid: 256 blocks (1 per CU) = b(8) x ohg(32), 512 threads (8 waves: 4 rows x 2 cout-halves).
// lA: 5-slot circular row window [132 iw+halo][64 ch] XOR-swizzled; prefetch at kw==2.
// lB: double-buffered [128 cout][64 ch]; next pos prefetched each round.
// Sync: counted-vmcnt rounds (T4) — {stage; s_waitcnt vmcnt(C); s_barrier; compute; s_barrier}.
// C = ops issued THIS round, so prior round's DMA has landed but this round's stays in flight
// (no per-round drain — the round-0/1 __syncthreads drained every prefetch it had just issued).
#define ASLOT 8448  // shorts per lA slot (132 rows * 64 ch)
__global__ __launch_bounds__(512, 2) void conv_kernel(const __hip_bfloat16* __restrict__ up,
                                                      const __hip_bfloat16* __restrict__ Wr,
                                                      float* __restrict__ out,
                                                      float* __restrict__ gstats) {
  __shared__ __align__(16) unsigned short lA[5 * ASLOT];     // 84480 B
  __shared__ __align__(16) unsigned short lB[2][128 * 64];   // 32768 B
  __shared__ float lsum[128], lssq[128];

  const int tid = threadIdx.x;
  const int lane = tid & 63;
  const int wave = tid >> 6;
  const int wm = wave >> 1;   // output row within 4-row group
  const int wn = wave & 1;    // cout half
  const int lane15 = lane & 15;
  const int quad = lane >> 4;
  const int wb = wave << 6;   // wave chunk base

  const int bid = blockIdx.x;
  const int orig = ((bid & 7) << 5) | (bid >> 3);  // XCD-chunked: each XCD owns one batch image
  const int b = orig >> 5;
  const int oh0 = (orig & 31) << 2;

  const f4v zero4 = {0.f, 0.f, 0.f, 0.f};
  if (tid < 128) { lsum[tid] = 0.f; lssq[tid] = 0.f; }
  // zero kw-halo rows (0,1,130,131 <-> iw -2,-1,128,129) of all 5 slots; never re-staged
  if (tid < 160) {
    int s = tid >> 5, j = tid & 31;
    int rsel = j >> 3;
    int r = (rsel < 2) ? rsel : (128 + rsel);
    *(f4v*)&lA[s * ASLOT + (r * 8 + (j & 7)) * 8] = zero4;
  }

  auto stageA = [&](int slot, const __hip_bfloat16* uprow) {  // rows 2..129 (iw 0..127), 2 ops/wave
#pragma unroll
    for (int t = 0; t < 2; ++t) {
      int pl = t * 512 + wb + lane;  // 0..1023
      int riw = pl >> 3, pc = pl & 7;
      int r = riw + 2;
      int cq = pc ^ (r & 7);
      async_copy16(uprow + riw * 256 + cq * 8, (void*)&lA[slot * ASLOT + (16 + t * 512 + wb) * 8]);
    }
  };
  auto stageB = [&](const __hip_bfloat16* wsrc, int bsel) {  // [128 cout][64 ch], 2 ops/wave
#pragma unroll
    for (int t = 0; t < 2; ++t) {
      int pl = t * 512 + wb + lane;
      int n = pl >> 3, pc = pl & 7;
      int cq = pc ^ (n & 7);
      async_copy16(wsrc + n * 256 + cq * 8, (void*)&lB[bsel][(t * 512 + wb) * 8]);
    }
  };

  f4v acc[8][4];
#pragma unroll
  for (int i = 0; i < 8; ++i)
#pragma unroll
    for (int j = 0; j < 4; ++j) acc[i][j] = zero4;

  // ---- prologue: prime lA rows oh0-2..oh0+1 (cb=0) + lB pos0 (cb=0)
  for (int rr = 0; rr < 4; ++rr) {
    int ih = oh0 + rr - 2;
    if ((unsigned)ih < 128u)
      stageA(ih % 5, up + (size_t)(b * 128 + ih) * 32768);
  }
  stageB(Wr, 0);
  __syncthreads();  // drains prologue DMA + makes halo zeros / lsum init visible (one-time)

  int buf = 0;
  for (int cb = 0; cb < 4; ++cb) {
    const int c0 = cb << 6;
    for (int kh = 0; kh < 5; ++kh) {
      const int ih = oh0 + wm + kh - 2;
      const bool rowok = (unsigned)ih < 128u;
      const int abase = rowok ? (ih % 5) * ASLOT : 0;
      for (int kw = 0; kw < 5; ++kw) {
        const int pos = kh * 5 + kw;
        // ---- stage phase (all counts block-uniform) ----
        if (cb != 0 && kh == 0 && kw == 0) {  // cb boundary: re-prime window at new channels
          for (int rr = 0; rr < 4; ++rr) {    // issued FIRST so vmcnt(2) below drains them
            int ihn = oh0 + rr - 2;
            if ((unsigned)ihn < 128u)
              stageA(ihn % 5, up + (size_t)(b * 128 + ihn) * 32768 + c0);
          }
        }
        if (pos < 24)      stageB(Wr + (size_t)(pos + 1) * 32768 + c0, buf ^ 1);
        else if (cb < 3)   stageB(Wr + (c0 + 64), buf ^ 1);  // next cb, pos0
        const bool extraA = (kw == 2) && (kh < 4) && (oh0 + kh + 2 < 128);
        if (extraA)  // lA row for kh+1; slot's old row last read 3 rounds ago
          stageA((oh0 + kh + 2) % 5, up + (size_t)(b * 128 + oh0 + kh + 2) * 32768 + c0);
        // ---- wait (counted: this round's ops stay in flight) + barrier ----
        if (pos == 24 && cb == 3) { WAITVM(0); }
        else if (extraA)          { WAITVM(4); }
        else                      { WAITVM(2); }
        block_barrier();
        // ---- compute ----
        if (rowok) {
#pragma unroll
          for (int ks = 0; ks < 2; ++ks) {
            const int cq = ks * 4 + quad;
            s8v a[8], bb[4];
#pragma unroll
            for (int mt = 0; mt < 8; ++mt) {
              int r = mt * 16 + lane15 + kw;  // shifted by kw; halo rows are zero
              a[mt] = *(const s8v*)&lA[abase + (r * 8 + (cq ^ (r & 7))) * 8];
            }
#pragma unroll
            for (int nt = 0; nt < 4; ++nt) {
              int n = (wn << 6) + nt * 16 + lane15;
              bb[nt] = *(const s8v*)&lB[buf][(n * 8 + (cq ^ (n & 7))) * 8];
            }
#pragma unroll
            for (int mt = 0; mt < 8; ++mt)
#pragma unroll
              for (int nt = 0; nt < 4; ++nt)
                acc[mt][nt] = __builtin_amdgcn_mfma_f32_16x16x32_bf16(a[mt], bb[nt], acc[mt][nt], 0, 0, 0);
          }
        }
        block_barrier();  // protects lA/lB reads from next round's DMA
        buf ^= 1;
      }
    }
  }

  // ---- epilogue: direct stores from acc (D: cout=lane&15, ow=mt*16+quad*4+reg) + stats
  __syncthreads();
  const int oh = oh0 + wm;
#pragma unroll
  for (int nt = 0; nt < 4; ++nt) {
    const int n = (wn << 6) + nt * 16 + lane15;
    float* oc = out + ((size_t)(b * 128 + n) * 128 + oh) * 128;
    float s = 0.f, ss = 0.f;
#pragma unroll
    for (int mt = 0; mt < 8; ++mt) {
      f4v v = acc[mt][nt];
      *(f4v*)&oc[mt * 16 + (quad << 2)] = v;
      s += v.x + v.y + v.z + v.w;
      ss += v.x * v.x + v.y * v.y + v.z * v.z + v.w * v.w;
    }
    s += __shfl_xor(s, 16, 64); ss += __shfl_xor(ss, 16, 64);
    s += __shfl_xor(s, 32, 64); ss += __shfl_xor(ss, 32, 64);
    if (quad == 0) { atomicAdd(&lsum[n], s); atomicAdd(&lssq[n], ss); }
  }
  __syncthreads();
  if (tid < 128) {
    atomicAdd(&gstats[tid], lsum[tid]);
    atomicAdd(&gstats[128 + tid], lssq[tid]);
  }
}

// ---------------- Normalize + ReLU in-place (scale/bias computed per-block; 1 channel/block) ----------------
__global__ void norm_kernel(float* __restrict__ out, const float* __restrict__ gstats,
                            const float* __restrict__ gamma, const float* __restrict__ beta) {
  __shared__ float ssb[2];
  const int c = (blockIdx.x >> 4) & 127;  // block covers 1024 float4 = one channel stretch
  if (threadIdx.x == 0) {
    float mean = gstats[c] * (1.f / 131072.f);
    float var = gstats[128 + c] * (1.f / 131072.f) - mean * mean;
    float inv = gamma[c] * rsqrtf(var + 1e-5f);
    ssb[0] = inv;
    ssb[1] = beta[c] - mean * inv;
  }
  __syncthreads();
  int i = blockIdx.x * 256 + threadIdx.x;  // float4 index, 4194304 total
  f4v v = ((f4v*)out)[i];
  float sc = ssb[0], bi = ssb[1];
  v.x = fmaxf(fmaf(v.x, sc, bi), 0.f);
  v.y = fmaxf(fmaf(v.y, sc, bi), 0.f);
  v.z = fmaxf(fmaf(v.z, sc, bi), 0.f);
  v.w = fmaxf(fmaf(v.w, sc, bi), 0.f);
  ((f4v*)out)[i] = v;
}

extern "C" void kernel_launch(void* const* d_in, const int* in_sizes, int n_in,
                              void* d_out, int out_size, void* d_ws, size_t ws_size,
                              hipStream_t stream) {
  (void)in_sizes; (void)n_in; (void)out_size; (void)ws_size;
  const float* x = (const float*)d_in[0];
  const float* W = (const float*)d_in[1];
  const float* gamma = (const float*)d_in[2];
  const float* beta = (const float*)d_in[3];
  float* out = (float*)d_out;
  char* ws = (char*)d_ws;
  __hip_bfloat16* up = (__hip_bfloat16*)ws;                       // 67,108,864 B
  __hip_bfloat16* Wr = (__hip_bfloat16*)(ws + 67108864);          // 1,638,400 B
  float* gstats = (float*)(ws + 67108864 + 1638400);              // sum[128], sumsq[128]

  wpack_kernel<<<128, 256, 0, stream>>>(W, Wr, gstats);           // also zeroes gstats
  upsample_kernel<<<512, 256, 0, stream>>>(x, up);
  conv_kernel<<<256, 512, 0, stream>>>(up, Wr, out, gstats);
  norm_kernel<<<16384, 256, 0, stream>>>(out, gstats, gamma, beta);
}

// Round 4
// 297.163 us; speedup vs baseline: 1.1409x; 1.0329x over previous
//
#include <hip/hip_runtime.h>
#include <hip/hip_bf16.h>
#include <stdint.h>

typedef short s8v __attribute__((ext_vector_type(8)));
typedef float f4v __attribute__((ext_vector_type(4)));

__device__ __forceinline__ void async_copy16(const void* gsrc, void* lds_dst) {
  __builtin_amdgcn_global_load_lds(
      (const __attribute__((address_space(1))) uint32_t*)(uintptr_t)gsrc,
      (__attribute__((address_space(3))) uint32_t*)(uint32_t)(uintptr_t)lds_dst,
      16, 0, 0);
}

#define WAITVM(N) asm volatile("s_waitcnt vmcnt(" #N ")" ::: "memory")
__device__ __forceinline__ void block_barrier() {
  asm volatile("" ::: "memory");
  __builtin_amdgcn_s_barrier();
  asm volatile("" ::: "memory");
}

// ---------------- W pack: [co][ci][kh][kw] fp32 -> [kh*5+kw][co][ci] bf16 ----------------
// One block per co; coalesced reads (contiguous 6400 floats) and coalesced writes (256-wide).
// Block 0 also zeroes gstats (replaces the hipMemsetAsync node).
__global__ __launch_bounds__(256) void wpack_kernel(const float* __restrict__ W,
                                                    __hip_bfloat16* __restrict__ Wr,
                                                    float* __restrict__ gstats) {
  __shared__ __hip_bfloat16 t[256 * 26];  // [ci][pos], pad to 26
  const int co = blockIdx.x;
  const int tid = threadIdx.x;
  if (co == 0) gstats[tid] = 0.f;  // 256 floats: sum[128], ssq[128]
  const float* src = W + co * 6400;
  for (int i = tid; i < 6400; i += 256) {
    int ci = i / 25;
    int pos = i - ci * 25;
    t[ci * 26 + pos] = __float2bfloat16(src[i]);
  }
  __syncthreads();
  for (int pos = 0; pos < 25; ++pos)
    Wr[pos * 32768 + co * 256 + tid] = t[tid * 26 + pos];
}

// ---------------- Upsample: x NCHW fp32 (8,256,64,64) -> up NHWC bf16 (8,128,128,256) ----------------
// grid: b(8) x cb(4,64ch) x ohb(8,16 rows) x owb(2,64 cols) = 512 blocks
__global__ __launch_bounds__(256, 2) void upsample_kernel(const float* __restrict__ x,
                                                          __hip_bfloat16* __restrict__ up) {
  __shared__ __hip_bfloat16 lx[10 * 48 * 66];  // [ih 10][iw 48][c 64 + 2 pad]
  const int tid = threadIdx.x;
  const int bx = blockIdx.x;
  const int owb = bx & 1;
  const int ohb = (bx >> 1) & 7;
  const int cb = (bx >> 4) & 3;
  const int b = bx >> 6;
  const int oh0 = ohb * 16, ow0 = owb * 64, c0 = cb * 64;
  const int ih0 = (oh0 >> 1) - 1;                    // may be -1
  const int iw_lo = (ow0 >> 1) - 1;
  const int aligned = (iw_lo < 0 ? 0 : iw_lo) & ~15; // 0 or 16

  for (int i = tid; i < 64 * 10 * 12; i += 256) {    // float4 loads along iw
    int c = i / 120;
    int rem = i - c * 120;
    int r = rem / 12;
    int w4 = (rem - r * 12) * 4;
    int gr = ih0 + r;
    gr = gr < 0 ? 0 : (gr > 63 ? 63 : gr);
    const float4 v = *(const float4*)&x[(((b * 256 + c0 + c) * 64) + gr) * 64 + aligned + w4];
    int base = (r * 48 + w4) * 66 + c;
    lx[base]       = __float2bfloat16(v.x);
    lx[base + 66]  = __float2bfloat16(v.y);
    lx[base + 132] = __float2bfloat16(v.z);
    lx[base + 198] = __float2bfloat16(v.w);
  }
  __syncthreads();

  // 2 channels per thread: b32 LDS reads, packed bf16x2 global stores
  const int c2 = (tid & 31) * 2;
  const int owq = tid >> 5;  // 0..7
  uint32_t* upu = (uint32_t*)up;
  for (int it = 0; it < 128; ++it) {
    int oh_l = it >> 3;
    int ow_l = (it & 7) * 8 + owq;
    int oh = oh0 + oh_l, ow = ow0 + ow_l;
    int ihA = (oh >> 1) - ((oh & 1) ^ 1);            // first tap row
    float wh = (oh & 1) ? 0.75f : 0.25f;             // its weight
    int iwA = (ow >> 1) - ((ow & 1) ^ 1);
    float wwt = (ow & 1) ? 0.75f : 0.25f;
    int r0 = ihA - ih0;                               // slot content is pre-clamped
    int w0 = (iwA < 0 ? 0 : iwA) - aligned;
    int w1t = iwA + 1; w1t = w1t > 63 ? 63 : w1t;
    int w1 = w1t - aligned;
    uint32_t t00 = *(const uint32_t*)&lx[(r0 * 48 + w0) * 66 + c2];
    uint32_t t01 = *(const uint32_t*)&lx[(r0 * 48 + w1) * 66 + c2];
    uint32_t t10 = *(const uint32_t*)&lx[((r0 + 1) * 48 + w0) * 66 + c2];
    uint32_t t11 = *(const uint32_t*)&lx[((r0 + 1) * 48 + w1) * 66 + c2];
    float wlo = wh * wwt, wlo1 = wh * (1.f - wwt);
    float whi = (1.f - wh) * wwt, whi1 = (1.f - wh) * (1.f - wwt);
    float vlo = wlo * __uint_as_float(t00 << 16) + wlo1 * __uint_as_float(t01 << 16) +
                whi * __uint_as_float(t10 << 16) + whi1 * __uint_as_float(t11 << 16);
    float vhi = wlo * __uint_as_float(t00 & 0xffff0000u) + wlo1 * __uint_as_float(t01 & 0xffff0000u) +
                whi * __uint_as_float(t10 & 0xffff0000u) + whi1 * __uint_as_float(t11 & 0xffff0000u);
    __hip_bfloat16 h0 = __float2bfloat16(vlo);
    __hip_bfloat16 h1 = __float2bfloat16(vhi);
    uint32_t pk = (uint32_t)(*(unsigned short*)&h0) | ((uint32_t)(*(unsigned short*)&h1) << 16);
    upu[((((size_t)(b * 128 + oh) * 128) + ow) * 256 + c0 + c2) >> 1] = pk;
  }
}

// ---------------- Conv: implicit GEMM, M=512 (4 rows x 128 ow) x N=128 couts, MFMA bf16 ----------------
// grid: 256 blocks (1 per CU) = b(8) x ohg(32), 512 threads (8 waves: 4 rows x 2 cout-halves).
// lA: 5-slot circular row window [132 iw+halo][64 ch] XOR-swizzled; prefetch at kw==2.
// lB: TRIPLE-buffered [128 cout][64 ch]; round r reads r%3, stages (r+2)%3 -> disjoint from
//     both the current read buffer and a 1-round-laggard's read buffer.
// Sync: ONE barrier per round {stage; s_waitcnt vmcnt(C); s_barrier; setprio(1) compute setprio(0)}.
// Fast waves run ahead into next round's stage/ds_reads while slow waves finish MFMAs ->
// LDS pipe and matrix pipe overlap via wave skew (they were ~serialized with 2 barriers/round).
// Extra barrier only at cb boundaries (lA window re-prime would collide with laggard reads).
#define ASLOT 8448  // shorts per lA slot (132 rows * 64 ch)
__global__ __launch_bounds__(512, 2) void conv_kernel(const __hip_bfloat16* __restrict__ up,
                                                      const __hip_bfloat16* __restrict__ Wr,
                                                      float* __restrict__ out,
                                                      float* __restrict__ gstats) {
  __shared__ __align__(16) unsigned short lA[5 * ASLOT];     // 84480 B
  __shared__ __align__(16) unsigned short lB[3][128 * 64];   // 49152 B
  __shared__ float lsum[128], lssq[128];

  const int tid = threadIdx.x;
  const int lane = tid & 63;
  const int wave = tid >> 6;
  const int wm = wave >> 1;   // output row within 4-row group
  const int wn = wave & 1;    // cout half
  const int lane15 = lane & 15;
  const int quad = lane >> 4;
  const int wb = wave << 6;   // wave chunk base

  const int bid = blockIdx.x;
  const int orig = ((bid & 7) << 5) | (bid >> 3);  // XCD-chunked: each XCD owns one batch image
  const int b = orig >> 5;
  const int oh0 = (orig & 31) << 2;

  const f4v zero4 = {0.f, 0.f, 0.f, 0.f};
  if (tid < 128) { lsum[tid] = 0.f; lssq[tid] = 0.f; }
  // zero kw-halo rows (0,1,130,131 <-> iw -2,-1,128,129) of all 5 slots; never re-staged
  if (tid < 160) {
    int s = tid >> 5, j = tid & 31;
    int rsel = j >> 3;
    int r = (rsel < 2) ? rsel : (128 + rsel);
    *(f4v*)&lA[s * ASLOT + (r * 8 + (j & 7)) * 8] = zero4;
  }

  auto stageA = [&](int slot, const __hip_bfloat16* uprow) {  // rows 2..129 (iw 0..127), 2 ops/wave
#pragma unroll
    for (int t = 0; t < 2; ++t) {
      int pl = t * 512 + wb + lane;  // 0..1023
      int riw = pl >> 3, pc = pl & 7;
      int r = riw + 2;
      int cq = pc ^ (r & 7);
      async_copy16(uprow + riw * 256 + cq * 8, (void*)&lA[slot * ASLOT + (16 + t * 512 + wb) * 8]);
    }
  };
  auto stageB = [&](const __hip_bfloat16* wsrc, int bsel) {  // [128 cout][64 ch], 2 ops/wave
#pragma unroll
    for (int t = 0; t < 2; ++t) {
      int pl = t * 512 + wb + lane;
      int n = pl >> 3, pc = pl & 7;
      int cq = pc ^ (n & 7);
      async_copy16(wsrc + n * 256 + cq * 8, (void*)&lB[bsel][(t * 512 + wb) * 8]);
    }
  };

  f4v acc[8][4];
#pragma unroll
  for (int i = 0; i < 8; ++i)
#pragma unroll
    for (int j = 0; j < 4; ++j) acc[i][j] = zero4;

  // ---- prologue: prime lA rows oh0-2..oh0+1 (cb=0) + lB pos0 (cb=0) into buffer 0
  for (int rr = 0; rr < 4; ++rr) {
    int ih = oh0 + rr - 2;
    if ((unsigned)ih < 128u)
      stageA(ih % 5, up + (size_t)(b * 128 + ih) * 32768);
  }
  stageB(Wr, 0);
  __syncthreads();  // drains prologue DMA + makes halo zeros / lsum init visible (one-time)

  int bcur = 0;
  for (int cb = 0; cb < 4; ++cb) {
    const int c0 = cb << 6;
    for (int kh = 0; kh < 5; ++kh) {
      const int ih = oh0 + wm + kh - 2;
      const bool rowok = (unsigned)ih < 128u;
      const int abase = rowok ? (ih % 5) * ASLOT : 0;
      for (int kw = 0; kw < 5; ++kw) {
        const int pos = kh * 5 + kw;
        const int bnext = (bcur == 2) ? 0 : bcur + 1;
        // ---- stage phase ----
        if (cb != 0 && kh == 0 && kw == 0) {  // cb boundary: re-prime window at new channels
          for (int rr = 0; rr < 4; ++rr) {    // issued FIRST so WAITVM(2) below drains them
            int ihn = oh0 + rr - 2;
            if ((unsigned)ihn < 128u)
              stageA(ihn % 5, up + (size_t)(b * 128 + ihn) * 32768 + c0);
          }
        }
        if (pos < 24)      stageB(Wr + (size_t)(pos + 1) * 32768 + c0, bnext);
        else if (cb < 3)   stageB(Wr + (c0 + 64), bnext);  // next cb, pos0
        const bool extraA = (kw == 2) && (kh < 4) && (oh0 + kh + 2 < 128);
        if (extraA)  // lA row for kh+1; target slot disjoint from rounds r-1..r read sets
          stageA((oh0 + kh + 2) % 5, up + (size_t)(b * 128 + oh0 + kh + 2) * 32768 + c0);
        // ---- counted wait (this round's ops stay in flight) + single barrier ----
        if (pos == 24 && cb == 3) { WAITVM(0); }
        else if (extraA)          { WAITVM(4); }
        else                      { WAITVM(2); }
        block_barrier();
        // ---- compute (prioritized; staging/lagging waves yield the issue slots) ----
        if (rowok) {
          __builtin_amdgcn_s_setprio(1);
#pragma unroll
          for (int ks = 0; ks < 2; ++ks) {
            const int cq = ks * 4 + quad;
            s8v a[8], bb[4];
#pragma unroll
            for (int mt = 0; mt < 8; ++mt) {
              int r = mt * 16 + lane15 + kw;  // shifted by kw; halo rows are zero
              a[mt] = *(const s8v*)&lA[abase + (r * 8 + (cq ^ (r & 7))) * 8];
            }
#pragma unroll
            for (int nt = 0; nt < 4; ++nt) {
              int n = (wn << 6) + nt * 16 + lane15;
              bb[nt] = *(const s8v*)&lB[bcur][(n * 8 + (cq ^ (n & 7))) * 8];
            }
#pragma unroll
            for (int mt = 0; mt < 8; ++mt)
#pragma unroll
              for (int nt = 0; nt < 4; ++nt)
                acc[mt][nt] = __builtin_amdgcn_mfma_f32_16x16x32_bf16(a[mt], bb[nt], acc[mt][nt], 0, 0, 0);
          }
          __builtin_amdgcn_s_setprio(0);
        }
        if (pos == 24 && cb < 3) block_barrier();  // protect cb-boundary lA re-prime (WAR)
        bcur = bnext;
      }
    }
  }

  // ---- epilogue: direct stores from acc (D: cout=lane&15, ow=mt*16+quad*4+reg) + stats
  const int oh = oh0 + wm;
#pragma unroll
  for (int nt = 0; nt < 4; ++nt) {
    const int n = (wn << 6) + nt * 16 + lane15;
    float* oc = out + ((size_t)(b * 128 + n) * 128 + oh) * 128;
    float s = 0.f, ss = 0.f;
#pragma unroll
    for (int mt = 0; mt < 8; ++mt) {
      f4v v = acc[mt][nt];
      *(f4v*)&oc[mt * 16 + (quad << 2)] = v;
      s += v.x + v.y + v.z + v.w;
      ss += v.x * v.x + v.y * v.y + v.z * v.z + v.w * v.w;
    }
    s += __shfl_xor(s, 16, 64); ss += __shfl_xor(ss, 16, 64);
    s += __shfl_xor(s, 32, 64); ss += __shfl_xor(ss, 32, 64);
    if (quad == 0) { atomicAdd(&lsum[n], s); atomicAdd(&lssq[n], ss); }
  }
  __syncthreads();
  if (tid < 128) {
    atomicAdd(&gstats[tid], lsum[tid]);
    atomicAdd(&gstats[128 + tid], lssq[tid]);
  }
}

// ---------------- Normalize + ReLU in-place, grid-stride (scale/bias recomputed per chunk;
// c is block-uniform per iteration so the gstats/gamma/beta loads are scalar L1 hits) ------
__global__ __launch_bounds__(256) void norm_kernel(float* __restrict__ out,
                                                   const float* __restrict__ gstats,
                                                   const float* __restrict__ gamma,
                                                   const float* __restrict__ beta) {
  for (int i = blockIdx.x * 256 + threadIdx.x; i < 4194304; i += 2048 * 256) {
    f4v v = ((f4v*)out)[i];
    int c = (i >> 12) & 127;
    float mean = gstats[c] * (1.f / 131072.f);
    float var = gstats[128 + c] * (1.f / 131072.f) - mean * mean;
    float sc = gamma[c] * rsqrtf(var + 1e-5f);
    float bi = beta[c] - mean * sc;
    v.x = fmaxf(fmaf(v.x, sc, bi), 0.f);
    v.y = fmaxf(fmaf(v.y, sc, bi), 0.f);
    v.z = fmaxf(fmaf(v.z, sc, bi), 0.f);
    v.w = fmaxf(fmaf(v.w, sc, bi), 0.f);
    ((f4v*)out)[i] = v;
  }
}

extern "C" void kernel_launch(void* const* d_in, const int* in_sizes, int n_in,
                              void* d_out, int out_size, void* d_ws, size_t ws_size,
                              hipStream_t stream) {
  (void)in_sizes; (void)n_in; (void)out_size; (void)ws_size;
  const float* x = (const float*)d_in[0];
  const float* W = (const float*)d_in[1];
  const float* gamma = (const float*)d_in[2];
  const float* beta = (const float*)d_in[3];
  float* out = (float*)d_out;
  char* ws = (char*)d_ws;
  __hip_bfloat16* up = (__hip_bfloat16*)ws;                       // 67,108,864 B
  __hip_bfloat16* Wr = (__hip_bfloat16*)(ws + 67108864);          // 1,638,400 B
  float* gstats = (float*)(ws + 67108864 + 1638400);              // sum[128], sumsq[128]

  wpack_kernel<<<128, 256, 0, stream>>>(W, Wr, gstats);           // also zeroes gstats
  upsample_kernel<<<512, 256, 0, stream>>>(x, up);
  conv_kernel<<<256, 512, 0, stream>>>(up, Wr, out, gstats);
  norm_kernel<<<2048, 256, 0, stream>>>(out, gstats, gamma, beta);
}